// Round 6
// baseline (193.482 us; speedup 1.0000x reference)
//
#include <hip/hip_runtime.h>
#include <hip/hip_bf16.h>
#include <stdint.h>

// ---- problem constants (B=2, T=2048, C=1024, H=16, hs=64) ----
#define BSZ   2
#define TT    2048
#define NH    16
#define HS    64
#define CC    1024
#define C3    3072
#define MT    4096            // B*T rows
#define E10   4.5399929762484854e-05f   // exp(-10)
#define SCL2  0.1803368801111204f       // 0.125 * log2(e)

typedef __bf16 bf16;
typedef __bf16 bf16x8 __attribute__((ext_vector_type(8)));
typedef float  f32x4  __attribute__((ext_vector_type(4)));
typedef short  s16x4  __attribute__((ext_vector_type(4)));

#define AS1 __attribute__((address_space(1)))
#define AS3 __attribute__((address_space(3)))

__device__ __forceinline__ void glds16(const bf16* g, bf16* l) {
    __builtin_amdgcn_global_load_lds((const AS1 void*)g, (AS3 void*)l, 16, 0, 0);
}

// =====================================================================
// Input dtype detector: flag=0 -> bf16 inputs, flag=1 -> fp32 inputs.
// =====================================================================
__global__ void detect_dtype(const uint16_t* __restrict__ x, int* __restrict__ flag) {
    __shared__ int cnt;
    if (threadIdx.x == 0) cnt = 0;
    __syncthreads();
    int local = 0;
    for (int i = threadIdx.x; i < 512; i += 256) {
        uint16_t u = x[i];
        int e = (u >> 7) & 0xFF;
        if (e >= 96 && e <= 159) local++;
    }
    atomicAdd(&cnt, local);
    __syncthreads();
    if (threadIdx.x == 0) *flag = (cnt >= 461) ? 0 : 1;
}

// fused fp32->bf16 converts for x / w_attn / w_proj (no-op when flag==0)
#define NX8  (MT * CC / 8)          // 524288
#define NWA8 (C3 * CC / 8)          // 393216
#define NWP8 (CC * CC / 8)          // 131072
__global__ __launch_bounds__(256)
void convert_all(const float* __restrict__ x, const float* __restrict__ wa,
                 const float* __restrict__ wp, bf16* __restrict__ xd,
                 bf16* __restrict__ wad, bf16* __restrict__ wpd,
                 const int* __restrict__ flag) {
    if (*flag == 0) return;
    long i = (long)blockIdx.x * 256 + threadIdx.x;
    const float* s; bf16* d; long off;
    if (i < NX8)             { s = x;  d = xd;  off = i; }
    else if (i < NX8 + NWA8) { s = wa; d = wad; off = i - NX8; }
    else                     { s = wp; d = wpd; off = i - NX8 - NWA8; }
    const float4* sp = reinterpret_cast<const float4*>(s) + off * 2;
    float4 a = sp[0], b = sp[1];
    bf16x8 r;
    r[0] = (bf16)a.x; r[1] = (bf16)a.y; r[2] = (bf16)a.z; r[3] = (bf16)a.w;
    r[4] = (bf16)b.x; r[5] = (bf16)b.y; r[6] = (bf16)b.z; r[7] = (bf16)b.w;
    reinterpret_cast<bf16x8*>(d)[off] = r;
}

// =====================================================================
// GEMM 128x128: C = A*B^T, dbuf single-barrier pipeline. Split store:
// col-blocks >= split_col write V directly in Vt layout (sigma-packed):
// tloc = mi*16+quad*4+r -> sigma(tloc) = quad*16+mi*4+r (r contiguous,
// 8B packed store). Kills the separate vtranspose pass.
// =====================================================================
__global__ __launch_bounds__(256)
void gemm_bt(const bf16* __restrict__ A0, const bf16* __restrict__ A1,
             const bf16* __restrict__ B0, const bf16* __restrict__ B1,
             void* __restrict__ Cmain, bf16* __restrict__ Cv,
             const int* __restrict__ flag,
             int M, int N, int K, int lda, int ldb, int ldc,
             int split_col, int cf32_dyn) {
    __shared__ bf16 As[2][128 * 32];
    __shared__ bf16 Bs[2][128 * 32];

    const int f = *flag;
    const bf16* A = f ? A1 : A0;
    const bf16* B = f ? B1 : B0;
    const int cf32 = cf32_dyn & f;

    const int tid  = threadIdx.x;
    const int lane = tid & 63;
    const int wave = tid >> 6;
    const int wm   = wave >> 1;
    const int wn   = wave & 1;
    const int quad = lane >> 4;
    const int l16  = lane & 15;

    const int row0 = blockIdx.y * 128;
    const int col0 = blockIdx.x * 128;

    const int srow = tid >> 2;
    const int skk  = (tid & 3) * 8;

    const bf16* Ap = A + (long)(row0 + srow) * lda + skk;
    const bf16* Bp = B + (long)(col0 + srow) * ldb + skk;

    auto stage = [&](int k0, int buf) {
        glds16(Ap + k0,                  &As[buf][wave * 512]);
        glds16(Ap + (long)64 * lda + k0, &As[buf][wave * 512 + 2048]);
        glds16(Bp + k0,                  &Bs[buf][wave * 512]);
        glds16(Bp + (long)64 * ldb + k0, &Bs[buf][wave * 512 + 2048]);
    };

    f32x4 acc[4][4] = {};
    stage(0, 0);

    for (int k0 = 0; k0 < K; k0 += 32) {
        const int buf = (k0 >> 5) & 1;
        __syncthreads();
        if (k0 + 32 < K) stage(k0 + 32, buf ^ 1);

        const bf16* Ac = As[buf];
        const bf16* Bc = Bs[buf];
        bf16x8 af[4], bfv[4];
#pragma unroll
        for (int mi = 0; mi < 4; ++mi)
            af[mi] = *reinterpret_cast<const bf16x8*>(&Ac[(wm * 64 + mi * 16 + l16) * 32 + quad * 8]);
#pragma unroll
        for (int ni = 0; ni < 4; ++ni)
            bfv[ni] = *reinterpret_cast<const bf16x8*>(&Bc[(wn * 64 + ni * 16 + l16) * 32 + quad * 8]);
#pragma unroll
        for (int mi = 0; mi < 4; ++mi)
#pragma unroll
            for (int ni = 0; ni < 4; ++ni)
                acc[mi][ni] = __builtin_amdgcn_mfma_f32_16x16x32_bf16(af[mi], bfv[ni], acc[mi][ni], 0, 0, 0);
    }

    if (split_col < 0 || col0 < split_col) {
        // main store (C/D layout: col=l16, row=quad*4+reg)
#pragma unroll
        for (int mi = 0; mi < 4; ++mi)
#pragma unroll
            for (int ni = 0; ni < 4; ++ni)
#pragma unroll
                for (int r = 0; r < 4; ++r) {
                    int row = row0 + wm * 64 + mi * 16 + quad * 4 + r;
                    int col = col0 + wn * 64 + ni * 16 + l16;
                    float v = acc[mi][ni][r];
                    if (cf32) ((float*)Cmain)[(long)row * ldc + col] = v;
                    else      ((bf16*)Cmain)[(long)row * ldc + col] = (bf16)v;
                }
    } else {
        // V store in Vt[bh][d][tc*64 + sigma(tloc)] layout
        const int h  = (col0 - split_col + wn * 64) >> 6;   // wave-uniform
        const int bq = row0 >> 11;
        const int tc = ((row0 & 2047) >> 6) + wm;
#pragma unroll
        for (int ni = 0; ni < 4; ++ni) {
            long vrow = (long)(bq * NH + h) * 64 + ni * 16 + l16;
#pragma unroll
            for (int mi = 0; mi < 4; ++mi) {
                bf16 outv[4];
#pragma unroll
                for (int r = 0; r < 4; ++r) outv[r] = (bf16)acc[mi][ni][r];
                *reinterpret_cast<uint2*>(&Cv[vrow * 2048 + tc * 64 + quad * 16 + mi * 4]) =
                    *reinterpret_cast<uint2*>(outv);
            }
        }
    }
}

// =====================================================================
// GEMM 128x64 (gemm2): grid 512 = 2 blocks/CU. acc[4][2].
// =====================================================================
__global__ __launch_bounds__(256)
void gemm_bt64(const bf16* __restrict__ A0, const bf16* __restrict__ A1,
               const bf16* __restrict__ B0, const bf16* __restrict__ B1,
               void* __restrict__ C, const int* __restrict__ flag,
               int M, int N, int K, int lda, int ldb, int ldc, int cf32_dyn) {
    __shared__ bf16 As[2][128 * 32];
    __shared__ bf16 Bs[2][64 * 32];

    const int f = *flag;
    const bf16* A = f ? A1 : A0;
    const bf16* B = f ? B1 : B0;
    const int cf32 = cf32_dyn & f;

    const int tid  = threadIdx.x;
    const int lane = tid & 63;
    const int wave = tid >> 6;
    const int wm   = wave >> 1;
    const int wn   = wave & 1;
    const int quad = lane >> 4;
    const int l16  = lane & 15;

    const int row0 = blockIdx.y * 128;
    const int col0 = blockIdx.x * 64;

    const int srow = tid >> 2;
    const int skk  = (tid & 3) * 8;

    const bf16* Ap = A + (long)(row0 + srow) * lda + skk;
    const bf16* Bp = B + (long)(col0 + srow) * ldb + skk;

    auto stage = [&](int k0, int buf) {
        glds16(Ap + k0,                  &As[buf][wave * 512]);
        glds16(Ap + (long)64 * lda + k0, &As[buf][wave * 512 + 2048]);
        glds16(Bp + k0,                  &Bs[buf][wave * 512]);
    };

    f32x4 acc[4][2] = {};
    stage(0, 0);

    for (int k0 = 0; k0 < K; k0 += 32) {
        const int buf = (k0 >> 5) & 1;
        __syncthreads();
        if (k0 + 32 < K) stage(k0 + 32, buf ^ 1);

        const bf16* Ac = As[buf];
        const bf16* Bc = Bs[buf];
        bf16x8 af[4], bfv[2];
#pragma unroll
        for (int mi = 0; mi < 4; ++mi)
            af[mi] = *reinterpret_cast<const bf16x8*>(&Ac[(wm * 64 + mi * 16 + l16) * 32 + quad * 8]);
#pragma unroll
        for (int ni = 0; ni < 2; ++ni)
            bfv[ni] = *reinterpret_cast<const bf16x8*>(&Bc[(wn * 32 + ni * 16 + l16) * 32 + quad * 8]);
#pragma unroll
        for (int mi = 0; mi < 4; ++mi)
#pragma unroll
            for (int ni = 0; ni < 2; ++ni)
                acc[mi][ni] = __builtin_amdgcn_mfma_f32_16x16x32_bf16(af[mi], bfv[ni], acc[mi][ni], 0, 0, 0);
    }

#pragma unroll
    for (int mi = 0; mi < 4; ++mi)
#pragma unroll
        for (int ni = 0; ni < 2; ++ni)
#pragma unroll
            for (int r = 0; r < 4; ++r) {
                int row = row0 + wm * 64 + mi * 16 + quad * 4 + r;
                int col = col0 + wn * 32 + ni * 16 + l16;
                float v = acc[mi][ni][r];
                if (cf32) ((float*)C)[(long)row * ldc + col] = v;
                else      ((bf16*)C)[(long)row * ldc + col] = (bf16)v;
            }
}

// =====================================================================
// Per-(bh,kt) V tile sums from Vt rows (sigma permutes within a tile ->
// sum invariant). 1024 blocks, coalesced 32B/thread.
// =====================================================================
__global__ __launch_bounds__(256)
void vtile2(const bf16* __restrict__ Vt, float* __restrict__ Vtile) {
    const int kt = blockIdx.x, bh = blockIdx.y;
    const int tid = threadIdx.x;
    const int d = tid >> 2, part = tid & 3;
    const bf16* p = Vt + ((long)bh * 64 + d) * 2048 + kt * 64 + part * 16;
    float s = 0.f;
#pragma unroll
    for (int i = 0; i < 2; ++i) {
        bf16x8 v = *reinterpret_cast<const bf16x8*>(p + i * 8);
#pragma unroll
        for (int j = 0; j < 8; ++j) s += (float)v[j];
    }
    s += __shfl_xor(s, 1, 64);
    s += __shfl_xor(s, 2, 64);
    if (part == 0) Vtile[((long)bh * 32 + kt) * 64 + d] = s;
}

// Suffix over 64-key tiles (tiny).
__global__ void vts_suffix(const float* __restrict__ Vtile, float* __restrict__ Vts) {
    const int bh = blockIdx.x, d = threadIdx.x;
    Vts[((long)bh * 33 + 32) * 64 + d] = 0.f;
    float acc = 0.f;
    for (int kt = 31; kt >= 0; --kt) {
        acc += Vtile[((long)bh * 32 + kt) * 64 + d];
        Vts[((long)bh * 33 + kt) * 64 + d] = acc;
    }
}

// =====================================================================
// Flash attention v7: SPLIT-K (flash-decoding). Inner loop = round-0
// verbatim (best measured). Work unit = (bh, chunk, seg): segment seg
// covers key-tiles [8*seg, min(8*seg+8, chunk+1)) -> longest serial
// chain drops 32 -> 8 tiles (diagnosed bottleneck: ~3100cyc/tile serial
// chain x 32 tiles = makespan). Soft-mask softmax has NO running max,
// so partials combine by plain addition of (O, lp); combine kernel adds
// Vts/E10 correction. Chunks 0..7 (1 segment) keep the direct path.
// sid enum: seg0: 0..31 (chunk 31-sid), seg1: 32..55 (chunk>=8),
// seg2: 56..71 (chunk>=16), seg3: 72..79 (chunk>=24). 2560 blocks.
// =====================================================================
__global__ __launch_bounds__(256)
void attn(bf16* __restrict__ qk, const bf16* __restrict__ Vt,
          const float* __restrict__ Vts, float* __restrict__ Opart,
          float* __restrict__ Lpart) {
    __shared__ bf16 Ks[2][64 * 64];
    __shared__ bf16 Vs[2][64 * 64];

    const int tid  = threadIdx.x;
    const int lane = tid & 63;
    const int wave = tid >> 6;
    const int quad = lane >> 4;
    const int l16  = lane & 15;

    const int f2   = blockIdx.x;            // 0..2559
    const int xcd  = f2 & 7;
    const int slot = f2 >> 3;               // 0..319
    const int bh   = (slot & 3) * 8 + xcd;
    const int sid  = slot >> 2;             // 0..79
    int seg, chunk;
    if      (sid < 32) { seg = 0; chunk = 31 - sid; }
    else if (sid < 56) { seg = 1; chunk = 31 - (sid - 32); }
    else if (sid < 72) { seg = 2; chunk = 31 - (sid - 56); }
    else               { seg = 3; chunk = 31 - (sid - 72); }

    const int b = bh >> 4, h = bh & 15;
    const int q0 = chunk * 64;
    const long rbase = (long)b * TT;
    const int ktfull = chunk + 1;
    const int kbeg = seg * 8;
    const int kend = (kbeg + 8 < ktfull) ? (kbeg + 8) : ktfull;

    const bf16* qp = qk + (rbase + q0 + wave * 16 + l16) * 2048 + h * HS;
    bf16x8 qf0 = *reinterpret_cast<const bf16x8*>(qp + quad * 8);
    bf16x8 qf1 = *reinterpret_cast<const bf16x8*>(qp + 32 + quad * 8);

    f32x4 O[4] = {};
    float lp = 0.f;

    const int rl  = lane >> 3;
    const int cs  = (lane & 7) ^ rl;
    const int row0dma = wave * 16 + rl;
    const bf16* kgb = qk + (rbase + row0dma) * 2048 + CC + h * HS + cs * 8;
    const bf16* vgb = Vt + ((long)(b * NH + h) * 64 + row0dma) * 2048 + cs * 8;
    const int sx = l16 & 7;

    auto stage = [&](int kt, int buf) {
        glds16(kgb + (long)(kt * 64) * 2048,     &Ks[buf][wave * 1024]);
        glds16(kgb + (long)(kt * 64 + 8) * 2048, &Ks[buf][wave * 1024 + 512]);
        glds16(vgb + kt * 64,                    &Vs[buf][wave * 1024]);
        glds16(vgb + 8 * 2048 + kt * 64,         &Vs[buf][wave * 1024 + 512]);
    };

    stage(kbeg, 0);

    for (int kt = kbeg; kt < kend; ++kt) {
        const int buf = kt & 1;             // kbeg even -> starts at 0
        __syncthreads();
        if (kt + 1 < kend) stage(kt + 1, buf ^ 1);

        const bf16* Kc = Ks[buf];
        const bf16* Vc = Vs[buf];

        bf16x8 kf0[4], kf1[4];
#pragma unroll
        for (int g = 0; g < 4; ++g) {
            const int krow = g * 16 + l16;
            kf0[g] = *reinterpret_cast<const bf16x8*>(&Kc[krow * 64 + ((quad ^ sx) * 8)]);
            kf1[g] = *reinterpret_cast<const bf16x8*>(&Kc[krow * 64 + (((4 + quad) ^ sx) * 8)]);
        }
        s16x4 vf[4][4];
#pragma unroll
        for (int dg = 0; dg < 4; ++dg) {
            const int vrow = dg * 16 + l16;
            union { uint4 u; s16x4 s[2]; } ua, ub;
            ua.u = *reinterpret_cast<const uint4*>(&Vc[vrow * 64 + (((2 * quad) ^ sx) * 8)]);
            ub.u = *reinterpret_cast<const uint4*>(&Vc[vrow * 64 + (((2 * quad + 1) ^ sx) * 8)]);
            vf[dg][0] = ua.s[0]; vf[dg][1] = ua.s[1];
            vf[dg][2] = ub.s[0]; vf[dg][3] = ub.s[1];
        }

        f32x4 S[4] = {};
#pragma unroll
        for (int g = 0; g < 4; ++g) {
            S[g] = __builtin_amdgcn_mfma_f32_16x16x32_bf16(kf0[g], qf0, S[g], 0, 0, 0);
            S[g] = __builtin_amdgcn_mfma_f32_16x16x32_bf16(kf1[g], qf1, S[g], 0, 0, 0);
        }

        const bool dtile = (kt == chunk);
        const int ql = wave * 16 + l16;
        s16x4 pk[4];
#pragma unroll
        for (int g = 0; g < 4; ++g) {
#pragma unroll
            for (int r = 0; r < 4; ++r) {
                float p = __builtin_exp2f(S[g][r] * SCL2);
                if (dtile) {
                    int kl = g * 16 + quad * 4 + r;
                    p = (kl > ql) ? E10 : p;
                }
                lp += p;
                union { bf16 b_; short s_; } u;
                u.b_ = (bf16)p;
                pk[g][r] = u.s_;
            }
        }

#pragma unroll
        for (int dg = 0; dg < 4; ++dg) {
            O[dg] = __builtin_amdgcn_mfma_f32_16x16x16bf16_1k(vf[dg][0], pk[0], O[dg], 0, 0, 0);
            O[dg] = __builtin_amdgcn_mfma_f32_16x16x16bf16_1k(vf[dg][1], pk[1], O[dg], 0, 0, 0);
            O[dg] = __builtin_amdgcn_mfma_f32_16x16x16bf16_1k(vf[dg][2], pk[2], O[dg], 0, 0, 0);
            O[dg] = __builtin_amdgcn_mfma_f32_16x16x16bf16_1k(vf[dg][3], pk[3], O[dg], 0, 0, 0);
        }
    }

    lp += __shfl_xor(lp, 16, 64);
    lp += __shfl_xor(lp, 32, 64);

    const int q = wave * 16 + l16;          // local q-row this lane owns

    if (chunk < 8) {
        // single-segment chunk: direct write (round-0 epilogue)
        const int nfut = TT - ktfull * 64;
        const float l = lp + (float)nfut * E10;
        const float invl = 1.0f / l;
        const float* vfp = Vts + ((long)bh * 33 + ktfull) * 64;

        bf16* yp = qk + (rbase + q0 + q) * 2048 + h * HS;
#pragma unroll
        for (int dg = 0; dg < 4; ++dg) {
            bf16 outv[4];
#pragma unroll
            for (int r = 0; r < 4; ++r) {
                float o = O[dg][r] + E10 * vfp[dg * 16 + quad * 4 + r];
                outv[r] = (bf16)(o * invl);
            }
            *reinterpret_cast<uint2*>(yp + dg * 16 + quad * 4) =
                *reinterpret_cast<uint2*>(outv);
        }
    } else {
        // partial write: O[q][d] f32, lp[q]
        const long pslot = (long)bh * 80 + sid;
        float* Op = Opart + pslot * 4096 + q * 64;
#pragma unroll
        for (int dg = 0; dg < 4; ++dg)
            *reinterpret_cast<f32x4*>(Op + dg * 16 + quad * 4) = O[dg];
        if (quad == 0) Lpart[pslot * 64 + q] = lp;
    }
}

// =====================================================================
// Split-K combine: chunks 8..31 (2..4 segments). Sum partials, apply
// Vts/E10 soft-mask correction, normalize, write bf16 y into qk.
// Grid (24 chunks, 32 bh) x 256; thread t -> q=t>>2, d-base=(t&3)*16.
// =====================================================================
__global__ __launch_bounds__(256)
void attn_combine(const float* __restrict__ Opart, const float* __restrict__ Lpart,
                  const float* __restrict__ Vts, bf16* __restrict__ qk) {
    const int c  = 8 + blockIdx.x;          // chunk 8..31
    const int bh = blockIdx.y;
    const int b = bh >> 4, h = bh & 15;
    const int nseg = (c < 16) ? 2 : (c < 24) ? 3 : 4;
    const int t = threadIdx.x;
    const int q  = t >> 2;
    const int dq = (t & 3) * 16;

    f32x4 of[4] = {};
    float lp = 0.f;
#pragma unroll
    for (int s = 0; s < 4; ++s) {
        if (s < nseg) {
            const int sb = (s == 0) ? 0 : (s == 1) ? 32 : (s == 2) ? 56 : 72;
            const long slot = (long)bh * 80 + sb + (31 - c);
            const float* Op = Opart + slot * 4096 + q * 64 + dq;
#pragma unroll
            for (int j = 0; j < 4; ++j)
                of[j] += *reinterpret_cast<const f32x4*>(Op + j * 4);
            lp += Lpart[slot * 64 + q];
        }
    }

    const int ktend = c + 1;
    const int nfut = TT - ktend * 64;
    const float l = lp + (float)nfut * E10;
    const float invl = 1.0f / l;
    const float* vfp = Vts + ((long)bh * 33 + ktend) * 64 + dq;

    bf16 outv[16];
#pragma unroll
    for (int j = 0; j < 4; ++j)
#pragma unroll
        for (int r = 0; r < 4; ++r)
            outv[j * 4 + r] = (bf16)((of[j][r] + E10 * vfp[j * 4 + r]) * invl);

    bf16* yp = qk + ((long)b * TT + c * 64 + q) * 2048 + h * HS + dq;
    *reinterpret_cast<uint4*>(yp)     = *reinterpret_cast<uint4*>(&outv[0]);
    *reinterpret_cast<uint4*>(yp + 8) = *reinterpret_cast<uint4*>(&outv[8]);
}

// =====================================================================
extern "C" void kernel_launch(void* const* d_in, const int* in_sizes, int n_in,
                              void* d_out, int out_size, void* d_ws, size_t ws_size,
                              hipStream_t stream) {
    const void* x      = d_in[0];
    const void* w_attn = d_in[1];
    const void* w_proj = d_in[2];

    // ws: qk | Vt | flag | Vts | wp_cvt | Vtile | Opart | Lpart  (~71 MB)
    char* ws = (char*)d_ws;
    bf16*  qk     = (bf16*)ws;                                    // 16,777,216 B
    bf16*  Vt     = (bf16*)(ws + (size_t)MT * 2048 * 2);          //  8,388,608 B
    char*  p2     = ws + (size_t)MT * 2048 * 2 + (size_t)32 * 64 * 2048 * 2;
    int*   flag   = (int*)p2;
    float* Vts    = (float*)(p2 + 256);                           //    270,336 B
    bf16*  wp_cvt = (bf16*)(p2 + 256 + 32 * 33 * 64 * 4);         //  2,097,152 B
    float* Vtile  = (float*)((char*)wp_cvt + (size_t)CC * CC * 2);//    262,144 B
    char*  p3     = (char*)Vtile + 32 * 32 * 64 * 4;
    float* Opart  = (float*)p3;                                   // 2560*16KB = 41,943,040 B
    float* Lpart  = (float*)(p3 + (size_t)2560 * 4096 * 4);       //    655,360 B

    // d_out scratch (dead-by-ordering): x_cvt/wa_cvt consumed by gemm1;
    // gemm2 is the only writer of d_out afterwards.
    bf16* x_cvt  = (bf16*)d_out;
    bf16* wa_cvt = (bf16*)d_out + (size_t)MT * CC;

    detect_dtype<<<1, 256, 0, stream>>>((const uint16_t*)x, flag);
    convert_all<<<(NX8 + NWA8 + NWP8) / 256, 256, 0, stream>>>(
        (const float*)x, (const float*)w_attn, (const float*)w_proj,
        x_cvt, wa_cvt, wp_cvt, flag);

    // gemm1: qkv projection. cols<2048 (Q,K) -> qk (ldc 2048);
    // cols>=2048 (V) -> Vt directly (sigma-packed layout).
    gemm_bt<<<dim3(C3 / 128, MT / 128), 256, 0, stream>>>(
        (const bf16*)x, x_cvt, (const bf16*)w_attn, wa_cvt, qk, Vt, flag,
        MT, C3, CC, CC, CC, /*ldc*/2048, /*split*/2048, /*cf32*/0);

    // V tile sums + suffix (soft-mask correction inputs)
    vtile2<<<dim3(32, BSZ * NH), 256, 0, stream>>>(Vt, Vtile);
    vts_suffix<<<dim3(BSZ * NH), dim3(64), 0, stream>>>(Vtile, Vts);

    // attention split-K main pass (2560 blocks) + combine (768 blocks)
    attn<<<dim3(2560), 256, 0, stream>>>(qk, Vt, Vts, Opart, Lpart);
    attn_combine<<<dim3(24, 32), 256, 0, stream>>>(Opart, Lpart, Vts, qk);

    // gemm2: out = y @ w_proj^T  [4096, 1024] — 128x64 tiles
    gemm_bt64<<<dim3(CC / 64, MT / 128), 256, 0, stream>>>(
        qk, qk, (const bf16*)w_proj, wp_cvt, d_out, flag,
        MT, CC, CC, /*lda*/2048, CC, CC, /*cf32*/1);
}

// Round 7
// 177.940 us; speedup vs baseline: 1.0873x; 1.0873x over previous
//
#include <hip/hip_runtime.h>
#include <hip/hip_bf16.h>
#include <stdint.h>

// ---- problem constants (B=2, T=2048, C=1024, H=16, hs=64) ----
#define BSZ   2
#define TT    2048
#define NH    16
#define HS    64
#define CC    1024
#define C3    3072
#define MT    4096            // B*T rows
#define E10   4.5399929762484854e-05f   // exp(-10)
#define SCL2  0.1803368801111204f       // 0.125 * log2(e)

typedef __bf16 bf16;
typedef __bf16 bf16x8 __attribute__((ext_vector_type(8)));
typedef float  f32x4  __attribute__((ext_vector_type(4)));
typedef short  s16x4  __attribute__((ext_vector_type(4)));

#define AS1 __attribute__((address_space(1)))
#define AS3 __attribute__((address_space(3)))

__device__ __forceinline__ void glds16(const bf16* g, bf16* l) {
    __builtin_amdgcn_global_load_lds((const AS1 void*)g, (AS3 void*)l, 16, 0, 0);
}

// =====================================================================
// convert_all with INLINE dtype detection (kills the detect kernel):
// every block samples x[0:512) uint16 exponents, computes flag locally;
// block 0 also publishes it for the gemm kernels.
// flag=0 -> bf16 inputs (no convert), flag=1 -> fp32 inputs.
// =====================================================================
#define NX8  (MT * CC / 8)          // 524288
#define NWA8 (C3 * CC / 8)          // 393216
#define NWP8 (CC * CC / 8)          // 131072
__global__ __launch_bounds__(256)
void convert_all(const float* __restrict__ x, const float* __restrict__ wa,
                 const float* __restrict__ wp, bf16* __restrict__ xd,
                 bf16* __restrict__ wad, bf16* __restrict__ wpd,
                 int* __restrict__ flag) {
    __shared__ int wsum[4];
    const int tid = threadIdx.x;
    const uint16_t* x16 = (const uint16_t*)x;
    int local = 0;
    {
        uint16_t u = x16[tid];
        int e = (u >> 7) & 0xFF; local += (e >= 96 && e <= 159);
        u = x16[tid + 256];
        e = (u >> 7) & 0xFF; local += (e >= 96 && e <= 159);
    }
    local += __shfl_xor(local, 1, 64);
    local += __shfl_xor(local, 2, 64);
    local += __shfl_xor(local, 4, 64);
    local += __shfl_xor(local, 8, 64);
    local += __shfl_xor(local, 16, 64);
    local += __shfl_xor(local, 32, 64);
    if ((tid & 63) == 0) wsum[tid >> 6] = local;
    __syncthreads();
    const int cnt = wsum[0] + wsum[1] + wsum[2] + wsum[3];
    const int f = (cnt >= 461) ? 0 : 1;
    if (blockIdx.x == 0 && tid == 0) *flag = f;
    if (f == 0) return;

    long i = (long)blockIdx.x * 256 + tid;
    const float* s; bf16* d; long off;
    if (i < NX8)             { s = x;  d = xd;  off = i; }
    else if (i < NX8 + NWA8) { s = wa; d = wad; off = i - NX8; }
    else                     { s = wp; d = wpd; off = i - NX8 - NWA8; }
    const float4* sp = reinterpret_cast<const float4*>(s) + off * 2;
    float4 a = sp[0], b = sp[1];
    bf16x8 r;
    r[0] = (bf16)a.x; r[1] = (bf16)a.y; r[2] = (bf16)a.z; r[3] = (bf16)a.w;
    r[4] = (bf16)b.x; r[5] = (bf16)b.y; r[6] = (bf16)b.z; r[7] = (bf16)b.w;
    reinterpret_cast<bf16x8*>(d)[off] = r;
}

// =====================================================================
// GEMM 128x128: C = A*B^T, dbuf single-barrier pipeline. Split store:
// col-blocks >= split_col write V directly in Vt layout (sigma-packed):
// tloc = mi*16+quad*4+r -> sigma(tloc) = quad*16+mi*4+r. V-branch also
// computes the per-(bh,tile) V column sums (Vtile) from acc in regs
// (in-reg sum over mi,r + 2 shuffles over quad) -> kills vtile2 kernel.
// =====================================================================
__global__ __launch_bounds__(256)
void gemm_bt(const bf16* __restrict__ A0, const bf16* __restrict__ A1,
             const bf16* __restrict__ B0, const bf16* __restrict__ B1,
             void* __restrict__ Cmain, bf16* __restrict__ Cv,
             float* __restrict__ Vtile,
             const int* __restrict__ flag,
             int M, int N, int K, int lda, int ldb, int ldc,
             int split_col, int cf32_dyn) {
    __shared__ bf16 As[2][128 * 32];
    __shared__ bf16 Bs[2][128 * 32];

    const int f = *flag;
    const bf16* A = f ? A1 : A0;
    const bf16* B = f ? B1 : B0;
    const int cf32 = cf32_dyn & f;

    const int tid  = threadIdx.x;
    const int lane = tid & 63;
    const int wave = tid >> 6;
    const int wm   = wave >> 1;
    const int wn   = wave & 1;
    const int quad = lane >> 4;
    const int l16  = lane & 15;

    const int row0 = blockIdx.y * 128;
    const int col0 = blockIdx.x * 128;

    const int srow = tid >> 2;
    const int skk  = (tid & 3) * 8;

    const bf16* Ap = A + (long)(row0 + srow) * lda + skk;
    const bf16* Bp = B + (long)(col0 + srow) * ldb + skk;

    auto stage = [&](int k0, int buf) {
        glds16(Ap + k0,                  &As[buf][wave * 512]);
        glds16(Ap + (long)64 * lda + k0, &As[buf][wave * 512 + 2048]);
        glds16(Bp + k0,                  &Bs[buf][wave * 512]);
        glds16(Bp + (long)64 * ldb + k0, &Bs[buf][wave * 512 + 2048]);
    };

    f32x4 acc[4][4] = {};
    stage(0, 0);

    for (int k0 = 0; k0 < K; k0 += 32) {
        const int buf = (k0 >> 5) & 1;
        __syncthreads();
        if (k0 + 32 < K) stage(k0 + 32, buf ^ 1);

        const bf16* Ac = As[buf];
        const bf16* Bc = Bs[buf];
        bf16x8 af[4], bfv[4];
#pragma unroll
        for (int mi = 0; mi < 4; ++mi)
            af[mi] = *reinterpret_cast<const bf16x8*>(&Ac[(wm * 64 + mi * 16 + l16) * 32 + quad * 8]);
#pragma unroll
        for (int ni = 0; ni < 4; ++ni)
            bfv[ni] = *reinterpret_cast<const bf16x8*>(&Bc[(wn * 64 + ni * 16 + l16) * 32 + quad * 8]);
#pragma unroll
        for (int mi = 0; mi < 4; ++mi)
#pragma unroll
            for (int ni = 0; ni < 4; ++ni)
                acc[mi][ni] = __builtin_amdgcn_mfma_f32_16x16x32_bf16(af[mi], bfv[ni], acc[mi][ni], 0, 0, 0);
    }

    if (split_col < 0 || col0 < split_col) {
        // main store (C/D layout: col=l16, row=quad*4+reg)
#pragma unroll
        for (int mi = 0; mi < 4; ++mi)
#pragma unroll
            for (int ni = 0; ni < 4; ++ni)
#pragma unroll
                for (int r = 0; r < 4; ++r) {
                    int row = row0 + wm * 64 + mi * 16 + quad * 4 + r;
                    int col = col0 + wn * 64 + ni * 16 + l16;
                    float v = acc[mi][ni][r];
                    if (cf32) ((float*)Cmain)[(long)row * ldc + col] = v;
                    else      ((bf16*)Cmain)[(long)row * ldc + col] = (bf16)v;
                }
    } else {
        // V store in Vt[bh][d][tc*64 + sigma(tloc)] layout
        const int h  = (col0 - split_col + wn * 64) >> 6;   // wave-uniform
        const int bq = row0 >> 11;
        const int tc = ((row0 & 2047) >> 6) + wm;
#pragma unroll
        for (int ni = 0; ni < 4; ++ni) {
            long vrow = (long)(bq * NH + h) * 64 + ni * 16 + l16;
#pragma unroll
            for (int mi = 0; mi < 4; ++mi) {
                bf16 outv[4];
#pragma unroll
                for (int r = 0; r < 4; ++r) outv[r] = (bf16)acc[mi][ni][r];
                *reinterpret_cast<uint2*>(&Cv[vrow * 2048 + tc * 64 + quad * 16 + mi * 4]) =
                    *reinterpret_cast<uint2*>(outv);
            }
        }
        // fused Vtile: per d-col sum over the 64-token tile
#pragma unroll
        for (int ni = 0; ni < 4; ++ni) {
            float s = 0.f;
#pragma unroll
            for (int mi = 0; mi < 4; ++mi)
#pragma unroll
                for (int r = 0; r < 4; ++r) s += acc[mi][ni][r];
            s += __shfl_xor(s, 16, 64);
            s += __shfl_xor(s, 32, 64);
            if (quad == 0)
                Vtile[((long)(bq * NH + h) * 32 + tc) * 64 + ni * 16 + l16] = s;
        }
    }
}

// =====================================================================
// GEMM 128x64 (gemm2): grid 512 = 2 blocks/CU. acc[4][2].
// =====================================================================
__global__ __launch_bounds__(256)
void gemm_bt64(const bf16* __restrict__ A0, const bf16* __restrict__ A1,
               const bf16* __restrict__ B0, const bf16* __restrict__ B1,
               void* __restrict__ C, const int* __restrict__ flag,
               int M, int N, int K, int lda, int ldb, int ldc, int cf32_dyn) {
    __shared__ bf16 As[2][128 * 32];
    __shared__ bf16 Bs[2][64 * 32];

    const int f = *flag;
    const bf16* A = f ? A1 : A0;
    const bf16* B = f ? B1 : B0;
    const int cf32 = cf32_dyn & f;

    const int tid  = threadIdx.x;
    const int lane = tid & 63;
    const int wave = tid >> 6;
    const int wm   = wave >> 1;
    const int wn   = wave & 1;
    const int quad = lane >> 4;
    const int l16  = lane & 15;

    const int row0 = blockIdx.y * 128;
    const int col0 = blockIdx.x * 64;

    const int srow = tid >> 2;
    const int skk  = (tid & 3) * 8;

    const bf16* Ap = A + (long)(row0 + srow) * lda + skk;
    const bf16* Bp = B + (long)(col0 + srow) * ldb + skk;

    auto stage = [&](int k0, int buf) {
        glds16(Ap + k0,                  &As[buf][wave * 512]);
        glds16(Ap + (long)64 * lda + k0, &As[buf][wave * 512 + 2048]);
        glds16(Bp + k0,                  &Bs[buf][wave * 512]);
    };

    f32x4 acc[4][2] = {};
    stage(0, 0);

    for (int k0 = 0; k0 < K; k0 += 32) {
        const int buf = (k0 >> 5) & 1;
        __syncthreads();
        if (k0 + 32 < K) stage(k0 + 32, buf ^ 1);

        const bf16* Ac = As[buf];
        const bf16* Bc = Bs[buf];
        bf16x8 af[4], bfv[2];
#pragma unroll
        for (int mi = 0; mi < 4; ++mi)
            af[mi] = *reinterpret_cast<const bf16x8*>(&Ac[(wm * 64 + mi * 16 + l16) * 32 + quad * 8]);
#pragma unroll
        for (int ni = 0; ni < 2; ++ni)
            bfv[ni] = *reinterpret_cast<const bf16x8*>(&Bc[(wn * 32 + ni * 16 + l16) * 32 + quad * 8]);
#pragma unroll
        for (int mi = 0; mi < 4; ++mi)
#pragma unroll
            for (int ni = 0; ni < 2; ++ni)
                acc[mi][ni] = __builtin_amdgcn_mfma_f32_16x16x32_bf16(af[mi], bfv[ni], acc[mi][ni], 0, 0, 0);
    }

#pragma unroll
    for (int mi = 0; mi < 4; ++mi)
#pragma unroll
        for (int ni = 0; ni < 2; ++ni)
#pragma unroll
            for (int r = 0; r < 4; ++r) {
                int row = row0 + wm * 64 + mi * 16 + quad * 4 + r;
                int col = col0 + wn * 32 + ni * 16 + l16;
                float v = acc[mi][ni][r];
                if (cf32) ((float*)C)[(long)row * ldc + col] = v;
                else      ((bf16*)C)[(long)row * ldc + col] = (bf16)v;
            }
}

// Suffix over 64-key tiles (tiny).
__global__ void vts_suffix(const float* __restrict__ Vtile, float* __restrict__ Vts) {
    const int bh = blockIdx.x, d = threadIdx.x;
    Vts[((long)bh * 33 + 32) * 64 + d] = 0.f;
    float acc = 0.f;
    for (int kt = 31; kt >= 0; --kt) {
        acc += Vtile[((long)bh * 32 + kt) * 64 + d];
        Vts[((long)bh * 33 + kt) * 64 + d] = acc;
    }
}

// =====================================================================
// Flash attention v8: v4 skeleton (64q x 64k, 4 waves, 1024 blocks,
// 3 LDS buffers, depth-2 counted-vmcnt prefetch, producer-XCD map)
// + CROSS-TILE SOFTWARE PIPELINE (T15): iteration t computes QK^T of
// tile t+1 (MFMA pipe) overlapped with softmax+PV of tile t (VALU/trans
// + MFMA). Kills the per-tile QK->stall->SM->stall->PV phase convoy
// that 6 structural variants left untouched (time ~44-50us with no
// pipe >50% in any of them). Named-register rotation (Sc/Sn, vc/vn)
// keeps all indexing static (rule #20).
// =====================================================================
__global__ __launch_bounds__(256, 3)
void attn(bf16* __restrict__ qk, const bf16* __restrict__ Vt,
          const float* __restrict__ Vts) {
    __shared__ bf16 Ks[3][64 * 64];
    __shared__ bf16 Vs[3][64 * 64];

    const int tid  = threadIdx.x;
    const int lane = tid & 63;
    const int wave = tid >> 6;
    const int quad = lane >> 4;
    const int l16  = lane & 15;

    const int f2   = blockIdx.x;            // 0..1023
    const int xcd  = f2 & 7;
    const int slot = f2 >> 3;               // 0..127
    const int u    = slot & 3;              // {b, h&1}
    const int chunk = 31 - (slot >> 2);     // heavy first
    const int h = xcd * 2 + (u & 1);        // producer XCD = h>>1
    const int b = u >> 1;
    const int bh = b * 16 + h;
    const int q0 = chunk * 64;
    const long rbase = (long)b * TT;
    const int ktend = chunk + 1;

    const bf16* qp = qk + (rbase + q0 + wave * 16 + l16) * 2048 + h * HS;
    bf16x8 qf0 = *reinterpret_cast<const bf16x8*>(qp + quad * 8);
    bf16x8 qf1 = *reinterpret_cast<const bf16x8*>(qp + 32 + quad * 8);

    f32x4 O[4] = {};
    float lp = 0.f;

    const int rl  = lane >> 3;
    const int cs  = (lane & 7) ^ rl;
    const int row0dma = wave * 16 + rl;
    const bf16* kgb = qk + (rbase + row0dma) * 2048 + CC + h * HS + cs * 8;
    const bf16* vgb = Vt + ((long)(b * NH + h) * 64 + row0dma) * 2048 + cs * 8;
    const int sx = l16 & 7;

    auto stage = [&](int kt, int bi) {
        glds16(kgb + (long)(kt * 64) * 2048,     &Ks[bi][wave * 1024]);
        glds16(kgb + (long)(kt * 64 + 8) * 2048, &Ks[bi][wave * 1024 + 512]);
        glds16(vgb + kt * 64,                    &Vs[bi][wave * 1024]);
        glds16(vgb + 8 * 2048 + kt * 64,         &Vs[bi][wave * 1024 + 512]);
    };

    auto qkTile = [&](int bi, f32x4* Sn) {
        const bf16* Kc = Ks[bi];
        bf16x8 kf0[4], kf1[4];
#pragma unroll
        for (int g = 0; g < 4; ++g) {
            const int krow = g * 16 + l16;
            kf0[g] = *reinterpret_cast<const bf16x8*>(&Kc[krow * 64 + ((quad ^ sx) * 8)]);
            kf1[g] = *reinterpret_cast<const bf16x8*>(&Kc[krow * 64 + (((4 + quad) ^ sx) * 8)]);
        }
        __builtin_amdgcn_s_setprio(1);
#pragma unroll
        for (int g = 0; g < 4; ++g) {
            Sn[g] = __builtin_amdgcn_mfma_f32_16x16x32_bf16(kf0[g], qf0, Sn[g], 0, 0, 0);
            Sn[g] = __builtin_amdgcn_mfma_f32_16x16x32_bf16(kf1[g], qf1, Sn[g], 0, 0, 0);
        }
        __builtin_amdgcn_s_setprio(0);
    };
    auto vTile = [&](int bi, s16x4 vf[4][4]) {
        const bf16* Vc = Vs[bi];
#pragma unroll
        for (int dg = 0; dg < 4; ++dg) {
            const int vrow = dg * 16 + l16;
            union { uint4 u4; s16x4 s[2]; } ua, ub;
            ua.u4 = *reinterpret_cast<const uint4*>(&Vc[vrow * 64 + (((2 * quad) ^ sx) * 8)]);
            ub.u4 = *reinterpret_cast<const uint4*>(&Vc[vrow * 64 + (((2 * quad + 1) ^ sx) * 8)]);
            vf[dg][0] = ua.s[0]; vf[dg][1] = ua.s[1];
            vf[dg][2] = ub.s[0]; vf[dg][3] = ub.s[1];
        }
    };

    // prologue: stage tiles 0,1 (clamped); QK(0) + V(0) into current regs
    stage(0, 0);
    stage(ktend > 1 ? 1 : 0, 1);
    asm volatile("s_waitcnt vmcnt(4)" ::: "memory");
    __builtin_amdgcn_s_barrier();
    __builtin_amdgcn_sched_barrier(0);

    f32x4 Sc[4] = {};
    s16x4 vc[4][4] = {};
    qkTile(0, Sc);
    vTile(0, vc);

    int rb = 1;                 // buffer of tile kt+1
    int sb = 2;                 // slot for stage(kt+2)
    for (int kt = 0; kt < ktend; ++kt) {
        int nkt = kt + 2; nkt = (nkt < ktend) ? nkt : (ktend - 1);
        stage(nkt, sb);
        // tile kt+1's 4 loads were issued last iter; after this wait only
        // the newer 4 (stage just issued) may remain outstanding.
        asm volatile("s_waitcnt vmcnt(4)" ::: "memory");
        __builtin_amdgcn_s_barrier();
        __builtin_amdgcn_sched_barrier(0);

        // QK^T + V-read of tile kt+1 (overlaps SM/PV of tile kt below)
        f32x4 Sn[4] = {};
        s16x4 vn[4][4] = {};
        if (kt + 1 < ktend) {
            qkTile(rb, Sn);
            vTile(rb, vn);
        }

        // softmax of tile kt (VALU/trans — independent of the QK above)
        const bool dtile = (kt == ktend - 1);
        const int ql = wave * 16 + l16;
        s16x4 pk[4];
#pragma unroll
        for (int g = 0; g < 4; ++g) {
#pragma unroll
            for (int r = 0; r < 4; ++r) {
                float p = __builtin_exp2f(Sc[g][r] * SCL2);
                if (dtile) {
                    int kl = g * 16 + quad * 4 + r;
                    p = (kl > ql) ? E10 : p;
                }
                lp += p;
                union { bf16 b_; short s_; } u2;
                u2.b_ = (bf16)p;
                pk[g][r] = u2.s_;
            }
        }

        // PV of tile kt
        __builtin_amdgcn_s_setprio(1);
#pragma unroll
        for (int dg = 0; dg < 4; ++dg) {
            O[dg] = __builtin_amdgcn_mfma_f32_16x16x16bf16_1k(vc[dg][0], pk[0], O[dg], 0, 0, 0);
            O[dg] = __builtin_amdgcn_mfma_f32_16x16x16bf16_1k(vc[dg][1], pk[1], O[dg], 0, 0, 0);
            O[dg] = __builtin_amdgcn_mfma_f32_16x16x16bf16_1k(vc[dg][2], pk[2], O[dg], 0, 0, 0);
            O[dg] = __builtin_amdgcn_mfma_f32_16x16x16bf16_1k(vc[dg][3], pk[3], O[dg], 0, 0, 0);
        }
        __builtin_amdgcn_s_setprio(0);

        // rotate pipeline registers (all static indices)
#pragma unroll
        for (int g = 0; g < 4; ++g) Sc[g] = Sn[g];
#pragma unroll
        for (int dg = 0; dg < 4; ++dg)
#pragma unroll
            for (int j = 0; j < 4; ++j) vc[dg][j] = vn[dg][j];

        rb = (rb == 2) ? 0 : rb + 1;
        sb = (sb == 2) ? 0 : sb + 1;
    }

    lp += __shfl_xor(lp, 16, 64);
    lp += __shfl_xor(lp, 32, 64);

    const int nfut = TT - ktend * 64;
    const float l = lp + (float)nfut * E10;
    const float invl = 1.0f / l;
    const float* vfp = Vts + ((long)bh * 33 + ktend) * 64;

    bf16* yp = qk + (rbase + q0 + wave * 16 + l16) * 2048 + h * HS;
#pragma unroll
    for (int dg = 0; dg < 4; ++dg) {
        bf16 outv[4];
#pragma unroll
        for (int r = 0; r < 4; ++r) {
            float o = O[dg][r] + E10 * vfp[dg * 16 + quad * 4 + r];
            outv[r] = (bf16)(o * invl);
        }
        *reinterpret_cast<uint2*>(yp + dg * 16 + quad * 4) =
            *reinterpret_cast<uint2*>(outv);
    }
}

// =====================================================================
extern "C" void kernel_launch(void* const* d_in, const int* in_sizes, int n_in,
                              void* d_out, int out_size, void* d_ws, size_t ws_size,
                              hipStream_t stream) {
    const void* x      = d_in[0];
    const void* w_attn = d_in[1];
    const void* w_proj = d_in[2];

    // ws (~27.8 MB): qk | Vt | flag | Vts | wp_cvt | Vtile
    char* ws = (char*)d_ws;
    bf16*  qk     = (bf16*)ws;                                    // 16,777,216 B
    bf16*  Vt     = (bf16*)(ws + (size_t)MT * 2048 * 2);          //  8,388,608 B
    char*  p2     = ws + (size_t)MT * 2048 * 2 + (size_t)32 * 64 * 2048 * 2;
    int*   flag   = (int*)p2;
    float* Vts    = (float*)(p2 + 256);                           //    270,336 B
    bf16*  wp_cvt = (bf16*)(p2 + 256 + 32 * 33 * 64 * 4);         //  2,097,152 B
    float* Vtile  = (float*)((char*)wp_cvt + (size_t)CC * CC * 2);//    262,144 B

    // d_out scratch (dead-by-ordering): x_cvt/wa_cvt consumed by gemm1;
    // gemm2 is the only writer of d_out afterwards.
    bf16* x_cvt  = (bf16*)d_out;
    bf16* wa_cvt = (bf16*)d_out + (size_t)MT * CC;

    // convert (with inline dtype detect; block 0 publishes flag)
    convert_all<<<(NX8 + NWA8 + NWP8) / 256, 256, 0, stream>>>(
        (const float*)x, (const float*)w_attn, (const float*)w_proj,
        x_cvt, wa_cvt, wp_cvt, flag);

    // gemm1: qkv projection. cols<2048 (Q,K) -> qk (ldc 2048);
    // cols>=2048 (V) -> Vt directly (sigma-packed) + fused Vtile sums.
    gemm_bt<<<dim3(C3 / 128, MT / 128), 256, 0, stream>>>(
        (const bf16*)x, x_cvt, (const bf16*)w_attn, wa_cvt, qk, Vt, Vtile, flag,
        MT, C3, CC, CC, CC, /*ldc*/2048, /*split*/2048, /*cf32*/0);

    // suffix over V tile sums (soft-mask correction inputs)
    vts_suffix<<<dim3(BSZ * NH), dim3(64), 0, stream>>>(Vtile, Vts);

    // attention (cross-tile pipelined); y overwrites Q columns of qk
    attn<<<dim3(1024), 256, 0, stream>>>(qk, Vt, Vts);

    // gemm2: out = y @ w_proj^T  [4096, 1024] — 128x64 tiles
    gemm_bt64<<<dim3(CC / 64, MT / 128), 256, 0, stream>>>(
        qk, qk, (const bf16*)w_proj, wp_cvt, d_out, flag,
        MT, CC, CC, /*lda*/2048, CC, CC, /*cf32*/1);
}

// Round 8
// 177.193 us; speedup vs baseline: 1.0919x; 1.0042x over previous
//
#include <hip/hip_runtime.h>
#include <hip/hip_bf16.h>
#include <stdint.h>

// ---- problem constants (B=2, T=2048, C=1024, H=16, hs=64) ----
#define BSZ   2
#define TT    2048
#define NH    16
#define HS    64
#define CC    1024
#define C3    3072
#define MT    4096            // B*T rows
#define E10   4.5399929762484854e-05f   // exp(-10)
#define SCL2  0.1803368801111204f       // 0.125 * log2(e)

typedef __bf16 bf16;
typedef __bf16 bf16x8 __attribute__((ext_vector_type(8)));
typedef float  f32x4  __attribute__((ext_vector_type(4)));
typedef short  s16x4  __attribute__((ext_vector_type(4)));

#define AS1 __attribute__((address_space(1)))
#define AS3 __attribute__((address_space(3)))

__device__ __forceinline__ void glds16(const bf16* g, bf16* l) {
    __builtin_amdgcn_global_load_lds((const AS1 void*)g, (AS3 void*)l, 16, 0, 0);
}

// =====================================================================
// convert_all with INLINE dtype detection: every block samples x[0:512)
// uint16 exponents, computes flag locally; block 0 publishes it.
// flag=0 -> bf16 inputs (no convert), flag=1 -> fp32 inputs.
// =====================================================================
#define NX8  (MT * CC / 8)          // 524288
#define NWA8 (C3 * CC / 8)          // 393216
#define NWP8 (CC * CC / 8)          // 131072
__global__ __launch_bounds__(256)
void convert_all(const float* __restrict__ x, const float* __restrict__ wa,
                 const float* __restrict__ wp, bf16* __restrict__ xd,
                 bf16* __restrict__ wad, bf16* __restrict__ wpd,
                 int* __restrict__ flag) {
    __shared__ int wsum[4];
    const int tid = threadIdx.x;
    const uint16_t* x16 = (const uint16_t*)x;
    int local = 0;
    {
        uint16_t u = x16[tid];
        int e = (u >> 7) & 0xFF; local += (e >= 96 && e <= 159);
        u = x16[tid + 256];
        e = (u >> 7) & 0xFF; local += (e >= 96 && e <= 159);
    }
    local += __shfl_xor(local, 1, 64);
    local += __shfl_xor(local, 2, 64);
    local += __shfl_xor(local, 4, 64);
    local += __shfl_xor(local, 8, 64);
    local += __shfl_xor(local, 16, 64);
    local += __shfl_xor(local, 32, 64);
    if ((tid & 63) == 0) wsum[tid >> 6] = local;
    __syncthreads();
    const int cnt = wsum[0] + wsum[1] + wsum[2] + wsum[3];
    const int f = (cnt >= 461) ? 0 : 1;
    if (blockIdx.x == 0 && tid == 0) *flag = f;
    if (f == 0) return;

    long i = (long)blockIdx.x * 256 + tid;
    const float* s; bf16* d; long off;
    if (i < NX8)             { s = x;  d = xd;  off = i; }
    else if (i < NX8 + NWA8) { s = wa; d = wad; off = i - NX8; }
    else                     { s = wp; d = wpd; off = i - NX8 - NWA8; }
    const float4* sp = reinterpret_cast<const float4*>(s) + off * 2;
    float4 a = sp[0], b = sp[1];
    bf16x8 r;
    r[0] = (bf16)a.x; r[1] = (bf16)a.y; r[2] = (bf16)a.z; r[3] = (bf16)a.w;
    r[4] = (bf16)b.x; r[5] = (bf16)b.y; r[6] = (bf16)b.z; r[7] = (bf16)b.w;
    reinterpret_cast<bf16x8*>(d)[off] = r;
}

// =====================================================================
// GEMM 128x128: C = A*B^T, dbuf single-barrier pipeline. Split store:
// col-blocks >= split_col write V directly in Vt layout (sigma-packed):
// tloc = mi*16+quad*4+r -> sigma(tloc) = quad*16+mi*4+r. V-branch also
// computes the per-(bh,tile) V column sums (Vtile) from acc in regs.
// =====================================================================
__global__ __launch_bounds__(256)
void gemm_bt(const bf16* __restrict__ A0, const bf16* __restrict__ A1,
             const bf16* __restrict__ B0, const bf16* __restrict__ B1,
             void* __restrict__ Cmain, bf16* __restrict__ Cv,
             float* __restrict__ Vtile,
             const int* __restrict__ flag,
             int M, int N, int K, int lda, int ldb, int ldc,
             int split_col, int cf32_dyn) {
    __shared__ bf16 As[2][128 * 32];
    __shared__ bf16 Bs[2][128 * 32];

    const int f = *flag;
    const bf16* A = f ? A1 : A0;
    const bf16* B = f ? B1 : B0;
    const int cf32 = cf32_dyn & f;

    const int tid  = threadIdx.x;
    const int lane = tid & 63;
    const int wave = tid >> 6;
    const int wm   = wave >> 1;
    const int wn   = wave & 1;
    const int quad = lane >> 4;
    const int l16  = lane & 15;

    const int row0 = blockIdx.y * 128;
    const int col0 = blockIdx.x * 128;

    const int srow = tid >> 2;
    const int skk  = (tid & 3) * 8;

    const bf16* Ap = A + (long)(row0 + srow) * lda + skk;
    const bf16* Bp = B + (long)(col0 + srow) * ldb + skk;

    auto stage = [&](int k0, int buf) {
        glds16(Ap + k0,                  &As[buf][wave * 512]);
        glds16(Ap + (long)64 * lda + k0, &As[buf][wave * 512 + 2048]);
        glds16(Bp + k0,                  &Bs[buf][wave * 512]);
        glds16(Bp + (long)64 * ldb + k0, &Bs[buf][wave * 512 + 2048]);
    };

    f32x4 acc[4][4] = {};
    stage(0, 0);

    for (int k0 = 0; k0 < K; k0 += 32) {
        const int buf = (k0 >> 5) & 1;
        __syncthreads();
        if (k0 + 32 < K) stage(k0 + 32, buf ^ 1);

        const bf16* Ac = As[buf];
        const bf16* Bc = Bs[buf];
        bf16x8 af[4], bfv[4];
#pragma unroll
        for (int mi = 0; mi < 4; ++mi)
            af[mi] = *reinterpret_cast<const bf16x8*>(&Ac[(wm * 64 + mi * 16 + l16) * 32 + quad * 8]);
#pragma unroll
        for (int ni = 0; ni < 4; ++ni)
            bfv[ni] = *reinterpret_cast<const bf16x8*>(&Bc[(wn * 64 + ni * 16 + l16) * 32 + quad * 8]);
#pragma unroll
        for (int mi = 0; mi < 4; ++mi)
#pragma unroll
            for (int ni = 0; ni < 4; ++ni)
                acc[mi][ni] = __builtin_amdgcn_mfma_f32_16x16x32_bf16(af[mi], bfv[ni], acc[mi][ni], 0, 0, 0);
    }

    if (split_col < 0 || col0 < split_col) {
        // main store (C/D layout: col=l16, row=quad*4+reg)
#pragma unroll
        for (int mi = 0; mi < 4; ++mi)
#pragma unroll
            for (int ni = 0; ni < 4; ++ni)
#pragma unroll
                for (int r = 0; r < 4; ++r) {
                    int row = row0 + wm * 64 + mi * 16 + quad * 4 + r;
                    int col = col0 + wn * 64 + ni * 16 + l16;
                    float v = acc[mi][ni][r];
                    if (cf32) ((float*)Cmain)[(long)row * ldc + col] = v;
                    else      ((bf16*)Cmain)[(long)row * ldc + col] = (bf16)v;
                }
    } else {
        // V store in Vt[bh][d][tc*64 + sigma(tloc)] layout
        const int h  = (col0 - split_col + wn * 64) >> 6;   // wave-uniform
        const int bq = row0 >> 11;
        const int tc = ((row0 & 2047) >> 6) + wm;
#pragma unroll
        for (int ni = 0; ni < 4; ++ni) {
            long vrow = (long)(bq * NH + h) * 64 + ni * 16 + l16;
#pragma unroll
            for (int mi = 0; mi < 4; ++mi) {
                bf16 outv[4];
#pragma unroll
                for (int r = 0; r < 4; ++r) outv[r] = (bf16)acc[mi][ni][r];
                *reinterpret_cast<uint2*>(&Cv[vrow * 2048 + tc * 64 + quad * 16 + mi * 4]) =
                    *reinterpret_cast<uint2*>(outv);
            }
        }
        // fused Vtile: per d-col sum over the 64-token tile
#pragma unroll
        for (int ni = 0; ni < 4; ++ni) {
            float s = 0.f;
#pragma unroll
            for (int mi = 0; mi < 4; ++mi)
#pragma unroll
                for (int r = 0; r < 4; ++r) s += acc[mi][ni][r];
            s += __shfl_xor(s, 16, 64);
            s += __shfl_xor(s, 32, 64);
            if (quad == 0)
                Vtile[((long)(bq * NH + h) * 32 + tc) * 64 + ni * 16 + l16] = s;
        }
    }
}

// =====================================================================
// GEMM 128x64 (gemm2): grid 512 = 2 blocks/CU. acc[4][2].
// =====================================================================
__global__ __launch_bounds__(256)
void gemm_bt64(const bf16* __restrict__ A0, const bf16* __restrict__ A1,
               const bf16* __restrict__ B0, const bf16* __restrict__ B1,
               void* __restrict__ C, const int* __restrict__ flag,
               int M, int N, int K, int lda, int ldb, int ldc, int cf32_dyn) {
    __shared__ bf16 As[2][128 * 32];
    __shared__ bf16 Bs[2][64 * 32];

    const int f = *flag;
    const bf16* A = f ? A1 : A0;
    const bf16* B = f ? B1 : B0;
    const int cf32 = cf32_dyn & f;

    const int tid  = threadIdx.x;
    const int lane = tid & 63;
    const int wave = tid >> 6;
    const int wm   = wave >> 1;
    const int wn   = wave & 1;
    const int quad = lane >> 4;
    const int l16  = lane & 15;

    const int row0 = blockIdx.y * 128;
    const int col0 = blockIdx.x * 64;

    const int srow = tid >> 2;
    const int skk  = (tid & 3) * 8;

    const bf16* Ap = A + (long)(row0 + srow) * lda + skk;
    const bf16* Bp = B + (long)(col0 + srow) * ldb + skk;

    auto stage = [&](int k0, int buf) {
        glds16(Ap + k0,                  &As[buf][wave * 512]);
        glds16(Ap + (long)64 * lda + k0, &As[buf][wave * 512 + 2048]);
        glds16(Bp + k0,                  &Bs[buf][wave * 512]);
    };

    f32x4 acc[4][2] = {};
    stage(0, 0);

    for (int k0 = 0; k0 < K; k0 += 32) {
        const int buf = (k0 >> 5) & 1;
        __syncthreads();
        if (k0 + 32 < K) stage(k0 + 32, buf ^ 1);

        const bf16* Ac = As[buf];
        const bf16* Bc = Bs[buf];
        bf16x8 af[4], bfv[2];
#pragma unroll
        for (int mi = 0; mi < 4; ++mi)
            af[mi] = *reinterpret_cast<const bf16x8*>(&Ac[(wm * 64 + mi * 16 + l16) * 32 + quad * 8]);
#pragma unroll
        for (int ni = 0; ni < 2; ++ni)
            bfv[ni] = *reinterpret_cast<const bf16x8*>(&Bc[(wn * 32 + ni * 16 + l16) * 32 + quad * 8]);
#pragma unroll
        for (int mi = 0; mi < 4; ++mi)
#pragma unroll
            for (int ni = 0; ni < 2; ++ni)
                acc[mi][ni] = __builtin_amdgcn_mfma_f32_16x16x32_bf16(af[mi], bfv[ni], acc[mi][ni], 0, 0, 0);
    }

#pragma unroll
    for (int mi = 0; mi < 4; ++mi)
#pragma unroll
        for (int ni = 0; ni < 2; ++ni)
#pragma unroll
            for (int r = 0; r < 4; ++r) {
                int row = row0 + wm * 64 + mi * 16 + quad * 4 + r;
                int col = col0 + wn * 32 + ni * 16 + l16;
                float v = acc[mi][ni][r];
                if (cf32) ((float*)C)[(long)row * ldc + col] = v;
                else      ((bf16*)C)[(long)row * ldc + col] = (bf16)v;
            }
}

// =====================================================================
// Flash attention v9: v8 skeleton (64q x 64k, 4 waves, 1024 blocks,
// 3 LDS buffers, depth-2 counted-vmcnt prefetch, cross-tile pipeline)
// + VALU diet (VALUBusy was 61%, the top counter):
//   - Q pre-scaled by SCL2 once  -> kills 16 v_mul/tile
//   - lp via ones-MFMA row-sum   -> kills 16 v_add/tile + end shuffles
//     (D[.][q] = sum_k P[k][q], identical across rows/quads at col=l16)
//   - Vts suffix computed in-block from Vtile -> kills vts_suffix kernel
// =====================================================================
__global__ __launch_bounds__(256, 3)
void attn(bf16* __restrict__ qk, const bf16* __restrict__ Vt,
          const float* __restrict__ Vtile) {
    __shared__ bf16 Ks[3][64 * 64];
    __shared__ bf16 Vs[3][64 * 64];
    __shared__ float Vpart[4][64];

    const int tid  = threadIdx.x;
    const int lane = tid & 63;
    const int wave = tid >> 6;
    const int quad = lane >> 4;
    const int l16  = lane & 15;

    const int f2   = blockIdx.x;            // 0..1023
    const int xcd  = f2 & 7;
    const int slot = f2 >> 3;               // 0..127
    const int u    = slot & 3;              // {b, h&1}
    const int chunk = 31 - (slot >> 2);     // heavy first
    const int h = xcd * 2 + (u & 1);        // producer XCD = h>>1
    const int b = u >> 1;
    const int bh = b * 16 + h;
    const int q0 = chunk * 64;
    const long rbase = (long)b * TT;
    const int ktend = chunk + 1;

    const bf16* qp = qk + (rbase + q0 + wave * 16 + l16) * 2048 + h * HS;
    bf16x8 qf0 = *reinterpret_cast<const bf16x8*>(qp + quad * 8);
    bf16x8 qf1 = *reinterpret_cast<const bf16x8*>(qp + 32 + quad * 8);
    // fold softmax scale into Q once: exp2(S*SCL2) = exp2((K . Q*SCL2))
#pragma unroll
    for (int j = 0; j < 8; ++j) {
        qf0[j] = (bf16)((float)qf0[j] * SCL2);
        qf1[j] = (bf16)((float)qf1[j] * SCL2);
    }

    f32x4 O[4] = {};
    f32x4 lpacc = {};
    const short one_bf16 = (short)0x3F80;
    const s16x4 ones = {one_bf16, one_bf16, one_bf16, one_bf16};

    const int rl  = lane >> 3;
    const int cs  = (lane & 7) ^ rl;
    const int row0dma = wave * 16 + rl;
    const bf16* kgb = qk + (rbase + row0dma) * 2048 + CC + h * HS + cs * 8;
    const bf16* vgb = Vt + ((long)(b * NH + h) * 64 + row0dma) * 2048 + cs * 8;
    const int sx = l16 & 7;

    auto stage = [&](int kt, int bi) {
        glds16(kgb + (long)(kt * 64) * 2048,     &Ks[bi][wave * 1024]);
        glds16(kgb + (long)(kt * 64 + 8) * 2048, &Ks[bi][wave * 1024 + 512]);
        glds16(vgb + kt * 64,                    &Vs[bi][wave * 1024]);
        glds16(vgb + 8 * 2048 + kt * 64,         &Vs[bi][wave * 1024 + 512]);
    };

    auto qkTile = [&](int bi, f32x4* Sn) {
        const bf16* Kc = Ks[bi];
        bf16x8 kf0[4], kf1[4];
#pragma unroll
        for (int g = 0; g < 4; ++g) {
            const int krow = g * 16 + l16;
            kf0[g] = *reinterpret_cast<const bf16x8*>(&Kc[krow * 64 + ((quad ^ sx) * 8)]);
            kf1[g] = *reinterpret_cast<const bf16x8*>(&Kc[krow * 64 + (((4 + quad) ^ sx) * 8)]);
        }
        __builtin_amdgcn_s_setprio(1);
#pragma unroll
        for (int g = 0; g < 4; ++g) {
            Sn[g] = __builtin_amdgcn_mfma_f32_16x16x32_bf16(kf0[g], qf0, Sn[g], 0, 0, 0);
            Sn[g] = __builtin_amdgcn_mfma_f32_16x16x32_bf16(kf1[g], qf1, Sn[g], 0, 0, 0);
        }
        __builtin_amdgcn_s_setprio(0);
    };
    auto vTile = [&](int bi, s16x4 vf[4][4]) {
        const bf16* Vc = Vs[bi];
#pragma unroll
        for (int dg = 0; dg < 4; ++dg) {
            const int vrow = dg * 16 + l16;
            union { uint4 u4; s16x4 s[2]; } ua, ub;
            ua.u4 = *reinterpret_cast<const uint4*>(&Vc[vrow * 64 + (((2 * quad) ^ sx) * 8)]);
            ub.u4 = *reinterpret_cast<const uint4*>(&Vc[vrow * 64 + (((2 * quad + 1) ^ sx) * 8)]);
            vf[dg][0] = ua.s[0]; vf[dg][1] = ua.s[1];
            vf[dg][2] = ub.s[0]; vf[dg][3] = ub.s[1];
        }
    };

    // prologue: stage tiles 0,1 (clamped); QK(0) + V(0) into current regs
    stage(0, 0);
    stage(ktend > 1 ? 1 : 0, 1);
    asm volatile("s_waitcnt vmcnt(4)" ::: "memory");
    __builtin_amdgcn_s_barrier();
    __builtin_amdgcn_sched_barrier(0);

    f32x4 Sc[4] = {};
    s16x4 vc[4][4] = {};
    qkTile(0, Sc);
    vTile(0, vc);

    int rb = 1;                 // buffer of tile kt+1
    int sb = 2;                 // slot for stage(kt+2)
    for (int kt = 0; kt < ktend; ++kt) {
        int nkt = kt + 2; nkt = (nkt < ktend) ? nkt : (ktend - 1);
        stage(nkt, sb);
        asm volatile("s_waitcnt vmcnt(4)" ::: "memory");
        __builtin_amdgcn_s_barrier();
        __builtin_amdgcn_sched_barrier(0);

        // QK^T + V-read of tile kt+1 (overlaps SM/PV of tile kt below)
        f32x4 Sn[4] = {};
        s16x4 vn[4][4] = {};
        if (kt + 1 < ktend) {
            qkTile(rb, Sn);
            vTile(rb, vn);
        }

        // softmax of tile kt (Q pre-scaled: p = exp2(S) directly)
        const bool dtile = (kt == ktend - 1);
        const int ql = wave * 16 + l16;
        s16x4 pk[4];
#pragma unroll
        for (int g = 0; g < 4; ++g) {
#pragma unroll
            for (int r = 0; r < 4; ++r) {
                float p = __builtin_exp2f(Sc[g][r]);
                if (dtile) {
                    int kl = g * 16 + quad * 4 + r;
                    p = (kl > ql) ? E10 : p;
                }
                union { bf16 b_; short s_; } u2;
                u2.b_ = (bf16)p;
                pk[g][r] = u2.s_;
            }
        }

        // PV of tile kt + lp row-sum via ones-MFMA (MFMA pipe, not VALU)
        __builtin_amdgcn_s_setprio(1);
#pragma unroll
        for (int dg = 0; dg < 4; ++dg) {
            O[dg] = __builtin_amdgcn_mfma_f32_16x16x16bf16_1k(vc[dg][0], pk[0], O[dg], 0, 0, 0);
            O[dg] = __builtin_amdgcn_mfma_f32_16x16x16bf16_1k(vc[dg][1], pk[1], O[dg], 0, 0, 0);
            O[dg] = __builtin_amdgcn_mfma_f32_16x16x16bf16_1k(vc[dg][2], pk[2], O[dg], 0, 0, 0);
            O[dg] = __builtin_amdgcn_mfma_f32_16x16x16bf16_1k(vc[dg][3], pk[3], O[dg], 0, 0, 0);
        }
        lpacc = __builtin_amdgcn_mfma_f32_16x16x16bf16_1k(ones, pk[0], lpacc, 0, 0, 0);
        lpacc = __builtin_amdgcn_mfma_f32_16x16x16bf16_1k(ones, pk[1], lpacc, 0, 0, 0);
        lpacc = __builtin_amdgcn_mfma_f32_16x16x16bf16_1k(ones, pk[2], lpacc, 0, 0, 0);
        lpacc = __builtin_amdgcn_mfma_f32_16x16x16bf16_1k(ones, pk[3], lpacc, 0, 0, 0);
        __builtin_amdgcn_s_setprio(0);

        // rotate pipeline registers (all static indices)
#pragma unroll
        for (int g = 0; g < 4; ++g) Sc[g] = Sn[g];
#pragma unroll
        for (int dg = 0; dg < 4; ++dg)
#pragma unroll
            for (int j = 0; j < 4; ++j) vc[dg][j] = vn[dg][j];

        rb = (rb == 2) ? 0 : rb + 1;
        sb = (sb == 2) ? 0 : sb + 1;
    }

    // in-block Vts suffix: sum Vtile[bh][kt][d] for kt in [ktend,32)
    {
        float s = 0.f;
        for (int kt = ktend + wave; kt < 32; kt += 4)
            s += Vtile[((long)bh * 32 + kt) * 64 + lane];
        Vpart[wave][lane] = s;
    }
    __syncthreads();

    // lp: every lane's lpacc[r] = sum_k P[k][q=l16] (uniform over r,quad)
    const int nfut = TT - ktend * 64;
    const float l = lpacc[0] + (float)nfut * E10;
    const float invl = 1.0f / l;

    bf16* yp = qk + (rbase + q0 + wave * 16 + l16) * 2048 + h * HS;
#pragma unroll
    for (int dg = 0; dg < 4; ++dg) {
        bf16 outv[4];
#pragma unroll
        for (int r = 0; r < 4; ++r) {
            const int d = dg * 16 + quad * 4 + r;
            float vts = Vpart[0][d] + Vpart[1][d] + Vpart[2][d] + Vpart[3][d];
            float o = O[dg][r] + E10 * vts;
            outv[r] = (bf16)(o * invl);
        }
        *reinterpret_cast<uint2*>(yp + dg * 16 + quad * 4) =
            *reinterpret_cast<uint2*>(outv);
    }
}

// =====================================================================
extern "C" void kernel_launch(void* const* d_in, const int* in_sizes, int n_in,
                              void* d_out, int out_size, void* d_ws, size_t ws_size,
                              hipStream_t stream) {
    const void* x      = d_in[0];
    const void* w_attn = d_in[1];
    const void* w_proj = d_in[2];

    // ws (~27.8 MB): qk | Vt | flag | (pad) | wp_cvt | Vtile
    char* ws = (char*)d_ws;
    bf16*  qk     = (bf16*)ws;                                    // 16,777,216 B
    bf16*  Vt     = (bf16*)(ws + (size_t)MT * 2048 * 2);          //  8,388,608 B
    char*  p2     = ws + (size_t)MT * 2048 * 2 + (size_t)32 * 64 * 2048 * 2;
    int*   flag   = (int*)p2;
    bf16*  wp_cvt = (bf16*)(p2 + 256 + 32 * 33 * 64 * 4);         //  2,097,152 B
    float* Vtile  = (float*)((char*)wp_cvt + (size_t)CC * CC * 2);//    262,144 B

    // d_out scratch (dead-by-ordering): x_cvt/wa_cvt consumed by gemm1;
    // gemm2 is the only writer of d_out afterwards.
    bf16* x_cvt  = (bf16*)d_out;
    bf16* wa_cvt = (bf16*)d_out + (size_t)MT * CC;

    // convert (with inline dtype detect; block 0 publishes flag)
    convert_all<<<(NX8 + NWA8 + NWP8) / 256, 256, 0, stream>>>(
        (const float*)x, (const float*)w_attn, (const float*)w_proj,
        x_cvt, wa_cvt, wp_cvt, flag);

    // gemm1: qkv projection. cols<2048 (Q,K) -> qk (ldc 2048);
    // cols>=2048 (V) -> Vt directly (sigma-packed) + fused Vtile sums.
    gemm_bt<<<dim3(C3 / 128, MT / 128), 256, 0, stream>>>(
        (const bf16*)x, x_cvt, (const bf16*)w_attn, wa_cvt, qk, Vt, Vtile, flag,
        MT, C3, CC, CC, CC, /*ldc*/2048, /*split*/2048, /*cf32*/0);

    // attention (cross-tile pipelined, in-block Vts suffix); y -> Q cols
    attn<<<dim3(1024), 256, 0, stream>>>(qk, Vt, Vtile);

    // gemm2: out = y @ w_proj^T  [4096, 1024] — 128x64 tiles
    gemm_bt64<<<dim3(CC / 64, MT / 128), 256, 0, stream>>>(
        qk, qk, (const bf16*)w_proj, wp_cvt, d_out, flag,
        MT, CC, CC, /*lda*/2048, CC, CC, /*cf32*/1);
}